// Round 13
// baseline (5728.827 us; speedup 1.0000x reference)
//
#include <hip/hip_runtime.h>

#define H_ 1024
#define B_ 128
#define S_ 512
#define V_ 128
#define E_ 256

// LDS layout (bytes)
#define ASH_OFF 0            // 32768  A fragments, XOR-swizzled
#define ZSH_OFF 32768        // 33792  [4 kg][16 row][132]
#define TSH_OFF 66560        // 67584  [128 v][132]
#define HSH_OFF 134144       // 1024   packed h slice (ushort[512])
#define XSH_OFF 135168       // 64     tokens
#define ROLE_OFF 135232      // 8      rg, cg
#define SMEM_TOTAL 135296

#define HXBUF 131072         // ushorts per hX buffer (256 slots * 512)

typedef __bf16 bf16x8 __attribute__((ext_vector_type(8)));
typedef float f32x4 __attribute__((ext_vector_type(4)));

// XCD-local coherent ops: sc0 bypasses L1 and hits the XCD's shared L2 (the
// common point for all 32 CUs on one XCD). No sc1 -> no MALL round trip.
__device__ __forceinline__ uint4 cload16(const unsigned short* p) {
  uint4 r;
  asm volatile("global_load_dwordx4 %0, %1, off sc0"
               : "=v"(r) : "v"(p) : "memory");
  return r;
}
__device__ __forceinline__ void cstore8(unsigned short* p, unsigned long long v) {
  asm volatile("global_store_dwordx2 %0, %1, off sc0"
               :: "v"(p), "v"(v) : "memory");
}
__device__ __forceinline__ unsigned fload_l2(const unsigned* p) {
  unsigned r;
  asm volatile("global_load_dword %0, %1, off sc0\n\ts_waitcnt vmcnt(0)"
               : "=v"(r) : "v"(p) : "memory");
  return r;
}
__device__ __forceinline__ unsigned fload_dev(const unsigned* p) {
  unsigned r;
  asm volatile("global_load_dword %0, %1, off sc0 sc1\n\ts_waitcnt vmcnt(0)"
               : "=v"(r) : "v"(p) : "memory");
  return r;
}
// Dual-scope flag publish: fast XCD-L2 copy + device-scope backup so a
// mis-placed consumer still makes progress (wrong-answer signal, never hang).
__device__ __forceinline__ void fstore_dual(unsigned* p, unsigned v) {
  asm volatile("global_store_dword %0, %1, off sc0\n\t"
               "global_store_dword %0, %1, off sc0 sc1"
               :: "v"(p), "v"(v) : "memory");
}

__device__ __forceinline__ unsigned short f2bf(float f) {
  unsigned u = __float_as_uint(f);
  u += 0x7fffu + ((u >> 16) & 1u);   // round-to-nearest-even
  return (unsigned short)(u >> 16);
}
__device__ __forceinline__ float sigf(float x) { return 1.0f / (1.0f + __expf(-x)); }
__device__ __forceinline__ float tanhfast(float x) { return 1.0f - 2.0f / (1.0f + __expf(2.0f * x)); }

// ---- tokproj[v][c] = emb[v]@Wx + b ; c = gate*1024 + j (natural layout) ----
__global__ void __launch_bounds__(256)
tokproj_kernel(const float* __restrict__ emb,
               const float* __restrict__ Wgx, const float* __restrict__ Wix,
               const float* __restrict__ Wfx, const float* __restrict__ Wox,
               const float* __restrict__ bg, const float* __restrict__ bi,
               const float* __restrict__ bf_, const float* __restrict__ bo,
               float* __restrict__ tokproj) {
  __shared__ float esh[E_];
  const int v = blockIdx.x;
  const int c = blockIdx.y * 256 + threadIdx.x;
  const int gate = c >> 10;
  const int j = c & 1023;
  const float* W = (gate == 0) ? Wgx : (gate == 1) ? Wix : (gate == 2) ? Wfx : Wox;
  const float* bias = (gate == 0) ? bg : (gate == 1) ? bi : (gate == 2) ? bf_ : bo;
  esh[threadIdx.x] = emb[v * E_ + threadIdx.x];
  __syncthreads();
  float acc = bias[j];
#pragma unroll 4
  for (int e = 0; e < E_; ++e) acc += esh[e] * W[e * H_ + j];
  tokproj[v * 4096 + c] = acc;
}

// ---- WhT[c][k] = bf16(Wh_gate[k][j]) ; c = gate*1024 + j ----
__global__ void __launch_bounds__(256)
wht_kernel(const float* __restrict__ Wgh, const float* __restrict__ Wih,
           const float* __restrict__ Wfh, const float* __restrict__ Woh,
           unsigned short* __restrict__ WhT) {
  const int c = blockIdx.x;
  const int gate = c >> 10;
  const int j = c & 1023;
  const float* W = (gate == 0) ? Wgh : (gate == 1) ? Wih : (gate == 2) ? Wfh : Woh;
  for (int k = threadIdx.x; k < H_; k += 256)
    WhT[c * H_ + k] = f2bf(W[k * H_ + j]);
}

// ---- xT[s][b] = x[b][s] ----
__global__ void __launch_bounds__(256)
xpose_kernel(const int* __restrict__ x, int* __restrict__ xT) {
  const int id = blockIdx.x * 256 + threadIdx.x;  // 65536
  const int s = id >> 7, b = id & 127;
  xT[s * 128 + b] = x[b * S_ + s];
}

// ---- persistent scan: 256 blocks x 512 thr (exactly 1 per CU, 32 per XCD) --
// Batch rows never mix in z = h@Wh, so exchange is confined to same-rg blocks.
// Role claim: rg = physical XCD id (s_getreg XCC_ID), cg = per-XCD atomic
// ticket 0..31 -> all 32 blocks sharing rg are on ONE XCD; their h exchange
// lives in that XCD's shared L2 (sc0 ops), never crossing the fabric.
// slot = rg*32+cg. hX[buf][slot][16 rows][32 cols] bf16, flags pub[slot*32].
__global__ void __launch_bounds__(512, 1)
lstm_scan(const int* __restrict__ xT, const float* __restrict__ tokproj,
          const unsigned short* __restrict__ WhT,
          unsigned short* __restrict__ hX, float* __restrict__ hfin,
          unsigned* __restrict__ pub, unsigned* __restrict__ cnt) {
  extern __shared__ char smem[];
  char* AshB = smem + ASH_OFF;
  float* Zsh = (float*)(smem + ZSH_OFF);
  float* tsh = (float*)(smem + TSH_OFF);
  unsigned short* hsh = (unsigned short*)(smem + HSH_OFF);
  int* xsh = (int*)(smem + XSH_OFF);
  int* role = (int*)(smem + ROLE_OFF);

  const int tid = threadIdx.x;
  const int w = tid >> 6;
  const int kg = w >> 1;          // k-group 0..3 (256 k each)
  const int ch = w & 1;           // col-half 0..1 (64 gate-cols each)
  const int lane = tid & 63;
  const int l15 = lane & 15;
  const int lq = lane >> 4;

  // ---- role claim: rg = XCD id, cg = ticket within XCD ----
  if (tid == 0) {
    unsigned xcc;
    asm volatile("s_getreg_b32 %0, hwreg(HW_REG_XCC_ID, 0, 32)" : "=s"(xcc));
    xcc &= 7u;
    unsigned old = __hip_atomic_fetch_add(cnt + xcc, 1u, __ATOMIC_RELAXED,
                                          __HIP_MEMORY_SCOPE_AGENT);
    role[0] = (int)xcc;
    role[1] = (int)(old & 31u);
  }
  __syncthreads();
  const int rg = role[0];
  const int cg = role[1];
  const int slot = rg * 32 + cg;

  // ---- one-time: tokproj slice -> LDS (block-local col j = gate*32+hu) ----
  for (int it = tid; it < 16384; it += 512) {
    const int v = it >> 7, j = it & 127;
    tsh[v * 132 + j] = tokproj[v * 4096 + (j >> 5) * 1024 + cg * 32 + (j & 31)];
  }
  // ---- one-time: B fragments -> registers ----
  uint4 breg[32];
#pragma unroll
  for (int kc = 0; kc < 8; ++kc) {
#pragma unroll
    for (int t = 0; t < 4; ++t) {
      const int j = ch * 64 + t * 16 + l15;
      const int c = ((j >> 5) << 10) + cg * 32 + (j & 31);
      breg[kc * 4 + t] =
          *(const uint4*)(WhT + c * 1024 + (kg * 8 + kc) * 32 + lq * 8);
    }
  }

  const int row_own = tid >> 5;      // 0..15
  const int hu = tid & 31;           // 0..31
  const int brow = rg * 16 + row_own;
  const int colg = cg * 32 + hu;

  // consumer binding: producer p (within rg), chunk sub-index t
  const int p = tid >> 4;            // 0..31
  const int t = tid & 15;            // 0..15
  const unsigned* myflag = pub + (rg * 32 + p) * 32;
  const unsigned short* srcbase = hX + (rg * 32 + p) * 512;  // + buf*HXBUF

  float creg = 0.f;
  // zero own h^0 slice (buffer 0) with XCD-local stores
  if (tid < 128) cstore8(hX + slot * 512 + tid * 4, 0ull);
  asm volatile("s_waitcnt vmcnt(0)" ::: "memory");
  __syncthreads();
  if (tid == 0) fstore_dual(pub + slot * 32, 1u);

  for (int s = 0; s < S_; ++s) {
    // ---- A: per-producer wait + coalesced XCD-local slice load ----
    int xv = 0;
    if (tid < 16) xv = xT[s * 128 + rg * 16 + tid];
    {
      const unsigned tgt = (unsigned)(s + 1);
      for (int sp = 1; ; ++sp) {
        const unsigned v = (sp & 63) ? fload_l2(myflag) : fload_dev(myflag);
        if (v >= tgt) break;
        __builtin_amdgcn_s_sleep(1);
      }
    }
    const unsigned short* src = srcbase + (s & 1) * HXBUF;
    uint4 av[4];
#pragma unroll
    for (int o = 0; o < 4; ++o)
      av[o] = cload16(src + (o * 16 + t) * 8);   // 16 lanes x 16 B contiguous
    asm volatile("s_waitcnt vmcnt(0)" ::: "memory");
    __builtin_amdgcn_sched_barrier(0);
#pragma unroll
    for (int o = 0; o < 4; ++o) {
      asm volatile("" : "+v"(av[o].x), "+v"(av[o].y), "+v"(av[o].z), "+v"(av[o].w));
    }

    __syncthreads();   // B: prior step fully done (AshB/hsh safe to overwrite)

    if (tid < 16) xsh[tid] = xv;
    // stage to LDS: chunk ci = o*16+t -> row r = ci>>2, k-chunk f = p*4+(ci&3)
#pragma unroll
    for (int o = 0; o < 4; ++o) {
      const int ci = o * 16 + t;
      const int f = p * 4 + (ci & 3);
      const int r = ci >> 2;
      *(uint4*)(AshB + f * 256 + ((r ^ (f & 15)) << 4)) = av[o];
    }
    __syncthreads();   // D

    // ---- MFMA: wave covers k [kg*256,+256) x cols [ch*64,+64) ----
    f32x4 acc0 = {0.f, 0.f, 0.f, 0.f}, acc1 = {0.f, 0.f, 0.f, 0.f};
    f32x4 acc2 = {0.f, 0.f, 0.f, 0.f}, acc3 = {0.f, 0.f, 0.f, 0.f};
#pragma unroll
    for (int kc = 0; kc < 8; ++kc) {
      const int f = (kg * 8 + kc) * 4 + lq;
      bf16x8 a = *(const bf16x8*)(AshB + f * 256 + ((l15 ^ (f & 15)) << 4));
      acc0 = __builtin_amdgcn_mfma_f32_16x16x32_bf16(a, __builtin_bit_cast(bf16x8, breg[kc * 4 + 0]), acc0, 0, 0, 0);
      acc1 = __builtin_amdgcn_mfma_f32_16x16x32_bf16(a, __builtin_bit_cast(bf16x8, breg[kc * 4 + 1]), acc1, 0, 0, 0);
      acc2 = __builtin_amdgcn_mfma_f32_16x16x32_bf16(a, __builtin_bit_cast(bf16x8, breg[kc * 4 + 2]), acc2, 0, 0, 0);
      acc3 = __builtin_amdgcn_mfma_f32_16x16x32_bf16(a, __builtin_bit_cast(bf16x8, breg[kc * 4 + 3]), acc3, 0, 0, 0);
    }
#pragma unroll
    for (int r_ = 0; r_ < 4; ++r_) {
      float* zr = Zsh + (kg * 16 + lq * 4 + r_) * 132 + ch * 64 + l15;
      zr[0] = acc0[r_]; zr[16] = acc1[r_]; zr[32] = acc2[r_]; zr[48] = acc3[r_];
    }
    __syncthreads();   // F

    // ---- gate pass: thread owns (row_own, hu) ----
    {
      const int xb = xsh[row_own];
      const float* tp = tsh + xb * 132;
      float z[4];
#pragma unroll
      for (int gate = 0; gate < 4; ++gate) {
        float zz = tp[gate * 32 + hu];
#pragma unroll
        for (int kgg = 0; kgg < 4; ++kgg)
          zz += Zsh[(kgg * 16 + row_own) * 132 + gate * 32 + hu];
        z[gate] = zz;
      }
      const float gv = tanhfast(z[0]);
      const float iv = sigf(z[1]);
      const float fv = sigf(z[2]);
      const float ov = sigf(z[3]);
      creg = gv * iv + creg * fv;
      const float hv = tanhfast(creg) * ov;
      hsh[row_own * 32 + hu] = f2bf(hv);
      if (s == S_ - 1) hfin[brow * H_ + colg] = hv;
    }
    __syncthreads();   // H

    // ---- packed publish: wave 0 stores the 1 KB slice + drains + flags ----
    // (vmcnt is wave-level; wave 0's drain covers all its lanes' stores)
    if (tid < 64) {
      const unsigned long long* hp = (const unsigned long long*)hsh;
      unsigned short* dst = hX + ((s + 1) & 1) * HXBUF + slot * 512;
      cstore8(dst + tid * 4, hp[tid]);
      cstore8(dst + 256 + tid * 4, hp[64 + tid]);
      asm volatile("s_waitcnt vmcnt(0)" ::: "memory");
      if (tid == 0) fstore_dual(pub + slot * 32, (unsigned)(s + 2));
    }
    // no barrier here: next-step polls/loads proceed; barrier B protects LDS
  }
}

// ---- p = hfin @ W_ph + b_p ; out = log_softmax(p) ----
__global__ void __launch_bounds__(256)
classify_kernel(const float* __restrict__ hfin, const float* __restrict__ Wph,
                const float* __restrict__ bp, float* __restrict__ out) {
  __shared__ float red[256 * 10];
  const int b = blockIdx.x, tid = threadIdx.x;
  float acc[10];
#pragma unroll
  for (int c = 0; c < 10; ++c) acc[c] = 0.f;
  for (int k = tid; k < H_; k += 256) {
    const float hv = hfin[b * H_ + k];
    const float* w = Wph + k * 10;
#pragma unroll
    for (int c = 0; c < 10; ++c) acc[c] += hv * w[c];
  }
#pragma unroll
  for (int c = 0; c < 10; ++c) red[tid * 10 + c] = acc[c];
  __syncthreads();
  for (int off = 128; off >= 1; off >>= 1) {
    if (tid < off) {
#pragma unroll
      for (int c = 0; c < 10; ++c) red[tid * 10 + c] += red[(tid + off) * 10 + c];
    }
    __syncthreads();
  }
  if (tid == 0) {
    float p[10];
    float m = -1e30f;
#pragma unroll
    for (int c = 0; c < 10; ++c) { p[c] = red[c] + bp[c]; m = fmaxf(m, p[c]); }
    float ssum = 0.f;
#pragma unroll
    for (int c = 0; c < 10; ++c) ssum += __expf(p[c] - m);
    const float lse = m + __logf(ssum);
#pragma unroll
    for (int c = 0; c < 10; ++c) out[b * 10 + c] = p[c] - lse;
  }
}

extern "C" void kernel_launch(void* const* d_in, const int* in_sizes, int n_in,
                              void* d_out, int out_size, void* d_ws, size_t ws_size,
                              hipStream_t stream) {
  (void)in_sizes; (void)n_in; (void)out_size; (void)ws_size;
  const int* x = (const int*)d_in[0];
  const float* emb = (const float*)d_in[1];
  const float* Wgx = (const float*)d_in[2];
  const float* Wgh = (const float*)d_in[3];
  const float* bg = (const float*)d_in[4];
  const float* Wix = (const float*)d_in[5];
  const float* Wih = (const float*)d_in[6];
  const float* bi = (const float*)d_in[7];
  const float* Wfx = (const float*)d_in[8];
  const float* Wfh = (const float*)d_in[9];
  const float* bf_ = (const float*)d_in[10];
  const float* Wox = (const float*)d_in[11];
  const float* Woh = (const float*)d_in[12];
  const float* bo = (const float*)d_in[13];
  const float* Wph = (const float*)d_in[14];
  const float* bp = (const float*)d_in[15];
  float* out = (float*)d_out;

  char* ws = (char*)d_ws;
  float* tokproj = (float*)ws;                                  // 2 MB
  unsigned short* WhT = (unsigned short*)(ws + 2097152);        // 8 MB
  unsigned short* hX = (unsigned short*)(ws + 10485760);        // 512 KB (2 bufs)
  float* hfin = (float*)(ws + 11010048);                        // 512 KB
  int* xT = (int*)(ws + 11538432);                              // 256 KB
  unsigned* pub = (unsigned*)(ws + 11800576);                   // 32 KB flags
  unsigned* cnt = (unsigned*)(ws + 11833344);                   // 32 B XCD tickets

  (void)hipMemsetAsync(pub, 0, 32768 + 64, stream);
  (void)hipFuncSetAttribute(reinterpret_cast<const void*>(lstm_scan),
                            hipFuncAttributeMaxDynamicSharedMemorySize, SMEM_TOTAL);

  tokproj_kernel<<<dim3(V_, 16), dim3(256), 0, stream>>>(
      emb, Wgx, Wix, Wfx, Wox, bg, bi, bf_, bo, tokproj);
  wht_kernel<<<dim3(4096), dim3(256), 0, stream>>>(Wgh, Wih, Wfh, Woh, WhT);
  xpose_kernel<<<dim3(256), dim3(256), 0, stream>>>(x, xT);
  lstm_scan<<<dim3(256), dim3(512), SMEM_TOTAL, stream>>>(
      xT, tokproj, WhT, hX, hfin, pub, cnt);
  classify_kernel<<<dim3(128), dim3(256), 0, stream>>>(hfin, Wph, bp, out);
}

// Round 14
// 1835.551 us; speedup vs baseline: 3.1210x; 3.1210x over previous
//
#include <hip/hip_runtime.h>

#define H_ 1024
#define B_ 128
#define S_ 512
#define V_ 128
#define E_ 256

// LDS layout (bytes)
#define ASH_OFF 0            // 32768  A fragments, XOR-swizzled
#define ZSH_OFF 32768        // 33792  [4 kg][16 row][132]
#define TSH_OFF 66560        // 67584  [128 v][132]
#define HSH_OFF 134144       // 1024   packed h slice (ushort[512])
#define XSH_OFF 135168       // 64     tokens
#define SMEM_TOTAL 135232

#define HXBUF 131072         // ushorts per hX buffer (256 blocks * 512)

typedef __bf16 bf16x8 __attribute__((ext_vector_type(8)));
typedef float f32x4 __attribute__((ext_vector_type(4)));

// Coherent (device-scope, L1/L2-bypass) 16-B load; ~1 lane-request/cyc at the
// CU (validated r7->r8->r9: step time tracks per-CU request count).
// NOTE r13: sc0-only (XCD-L2-scope) variants are 3x SLOWER despite correct
// placement — device scope through the MALL is the fast path on gfx950.
__device__ __forceinline__ uint4 cload16(const unsigned short* p) {
  uint4 r;
  asm volatile("global_load_dwordx4 %0, %1, off sc0 sc1"
               : "=v"(r) : "v"(p) : "memory");
  return r;
}
// Coherent 8-B store via compiler atomics (asm can't take wide inputs).
__device__ __forceinline__ void cstore8(unsigned short* p, unsigned long long v) {
  __hip_atomic_store((unsigned long long*)p, v, __ATOMIC_RELAXED,
                     __HIP_MEMORY_SCOPE_AGENT);
}

__device__ __forceinline__ unsigned short f2bf(float f) {
  unsigned u = __float_as_uint(f);
  u += 0x7fffu + ((u >> 16) & 1u);   // round-to-nearest-even
  return (unsigned short)(u >> 16);
}
__device__ __forceinline__ float sigf(float x) { return 1.0f / (1.0f + __expf(-x)); }
__device__ __forceinline__ float tanhfast(float x) { return 1.0f - 2.0f / (1.0f + __expf(2.0f * x)); }

// ---- tokproj[v][c] = emb[v]@Wx + b ; c = gate*1024 + j (natural layout) ----
__global__ void __launch_bounds__(256)
tokproj_kernel(const float* __restrict__ emb,
               const float* __restrict__ Wgx, const float* __restrict__ Wix,
               const float* __restrict__ Wfx, const float* __restrict__ Wox,
               const float* __restrict__ bg, const float* __restrict__ bi,
               const float* __restrict__ bf_, const float* __restrict__ bo,
               float* __restrict__ tokproj) {
  __shared__ float esh[E_];
  const int v = blockIdx.x;
  const int c = blockIdx.y * 256 + threadIdx.x;
  const int gate = c >> 10;
  const int j = c & 1023;
  const float* W = (gate == 0) ? Wgx : (gate == 1) ? Wix : (gate == 2) ? Wfx : Wox;
  const float* bias = (gate == 0) ? bg : (gate == 1) ? bi : (gate == 2) ? bf_ : bo;
  esh[threadIdx.x] = emb[v * E_ + threadIdx.x];
  __syncthreads();
  float acc = bias[j];
#pragma unroll 4
  for (int e = 0; e < E_; ++e) acc += esh[e] * W[e * H_ + j];
  tokproj[v * 4096 + c] = acc;
}

// ---- WhT[c][k] = bf16(Wh_gate[k][j]) ; c = gate*1024 + j ----
__global__ void __launch_bounds__(256)
wht_kernel(const float* __restrict__ Wgh, const float* __restrict__ Wih,
           const float* __restrict__ Wfh, const float* __restrict__ Woh,
           unsigned short* __restrict__ WhT) {
  const int c = blockIdx.x;
  const int gate = c >> 10;
  const int j = c & 1023;
  const float* W = (gate == 0) ? Wgh : (gate == 1) ? Wih : (gate == 2) ? Wfh : Woh;
  for (int k = threadIdx.x; k < H_; k += 256)
    WhT[c * H_ + k] = f2bf(W[k * H_ + j]);
}

// ---- xT[s][b] = x[b][s] ----
__global__ void __launch_bounds__(256)
xpose_kernel(const int* __restrict__ x, int* __restrict__ xT) {
  const int id = blockIdx.x * 256 + threadIdx.x;  // 65536
  const int s = id >> 7, b = id & 127;
  xT[s * 128 + b] = x[b * S_ + s];
}

// ---- persistent scan: 256 blocks x 512 thr (1 per CU) ----
// bid: rg = bid>>5 owns batch rows [rg*16,+16); cg = bid&31 owns hidden units
// [cg*32,+32). Exchange is producer-major: hX[buf][bid][row 0..16][col 0..32]
// bf16 (1 KB slice). Consumer thread tid is bound to producer p = tid>>4 of
// its own rg: polls pub[rg*32+p] only, then immediately loads 4 coalesced
// 16-B chunks of that slice. Slice chunk ci -> row ci>>2, k-chunk p*4+(ci&3).
__global__ void __launch_bounds__(512, 1)
lstm_scan(const int* __restrict__ xT, const float* __restrict__ tokproj,
          const unsigned short* __restrict__ WhT,
          unsigned short* __restrict__ hX, float* __restrict__ hfin,
          unsigned* __restrict__ pub) {
  extern __shared__ char smem[];
  char* AshB = smem + ASH_OFF;
  float* Zsh = (float*)(smem + ZSH_OFF);
  float* tsh = (float*)(smem + TSH_OFF);
  unsigned short* hsh = (unsigned short*)(smem + HSH_OFF);
  int* xsh = (int*)(smem + XSH_OFF);

  const int bid = blockIdx.x;
  const int rg = bid >> 5;
  const int cg = bid & 31;
  const int tid = threadIdx.x;
  const int w = tid >> 6;
  const int kg = w >> 1;          // k-group 0..3 (256 k each)
  const int ch = w & 1;           // col-half 0..1 (64 gate-cols each)
  const int lane = tid & 63;
  const int l15 = lane & 15;
  const int lq = lane >> 4;

  // ---- one-time: tokproj slice -> LDS (block-local col j = gate*32+hu) ----
  for (int it = tid; it < 16384; it += 512) {
    const int v = it >> 7, j = it & 127;
    tsh[v * 132 + j] = tokproj[v * 4096 + (j >> 5) * 1024 + cg * 32 + (j & 31)];
  }
  // ---- one-time: B fragments -> registers ----
  uint4 breg[32];
#pragma unroll
  for (int kc = 0; kc < 8; ++kc) {
#pragma unroll
    for (int t = 0; t < 4; ++t) {
      const int j = ch * 64 + t * 16 + l15;
      const int c = ((j >> 5) << 10) + cg * 32 + (j & 31);
      breg[kc * 4 + t] =
          *(const uint4*)(WhT + c * 1024 + (kg * 8 + kc) * 32 + lq * 8);
    }
  }

  const int row_own = tid >> 5;      // 0..15
  const int hu = tid & 31;           // 0..31
  const int brow = rg * 16 + row_own;
  const int colg = cg * 32 + hu;

  // consumer binding: producer p (within rg), chunk sub-index t
  const int p = tid >> 4;            // 0..31
  const int t = tid & 15;            // 0..15
  const unsigned* myflag = pub + (rg * 32 + p) * 32;
  const unsigned short* srcbase = hX + (rg * 32 + p) * 512;  // + buf*HXBUF

  float creg = 0.f;
  // zero own h^0 slice (buffer 0) with packed coherent stores
  if (tid < 128) cstore8(hX + bid * 512 + tid * 4, 0ull);
  asm volatile("s_waitcnt vmcnt(0)" ::: "memory");
  __syncthreads();
  if (tid == 0)
    __hip_atomic_store(pub + bid * 32, 1u, __ATOMIC_RELAXED, __HIP_MEMORY_SCOPE_AGENT);

  for (int s = 0; s < S_; ++s) {
    // ---- A: per-producer wait + coalesced slice load (overlapped) ----
    int xv = 0;
    if (tid < 16) xv = xT[s * 128 + rg * 16 + tid];
    {
      const unsigned tgt = (unsigned)(s + 1);
      while (__hip_atomic_load(myflag, __ATOMIC_RELAXED, __HIP_MEMORY_SCOPE_AGENT) < tgt)
        __builtin_amdgcn_s_sleep(1);
    }
    const unsigned short* src = srcbase + (s & 1) * HXBUF;
    uint4 av[4];
#pragma unroll
    for (int o = 0; o < 4; ++o)
      av[o] = cload16(src + (o * 16 + t) * 8);   // 16 lanes x 16 B contiguous
    asm volatile("s_waitcnt vmcnt(0)" ::: "memory");
    __builtin_amdgcn_sched_barrier(0);
#pragma unroll
    for (int o = 0; o < 4; ++o) {
      asm volatile("" : "+v"(av[o].x), "+v"(av[o].y), "+v"(av[o].z), "+v"(av[o].w));
    }

    __syncthreads();   // B: prior step fully done (AshB/hsh safe to overwrite)

    if (tid < 16) xsh[tid] = xv;
    // stage to LDS: chunk ci = o*16+t -> row r = ci>>2, k-chunk f = p*4+(ci&3)
#pragma unroll
    for (int o = 0; o < 4; ++o) {
      const int ci = o * 16 + t;
      const int f = p * 4 + (ci & 3);
      const int r = ci >> 2;
      *(uint4*)(AshB + f * 256 + ((r ^ (f & 15)) << 4)) = av[o];
    }
    __syncthreads();   // D

    // ---- MFMA: wave covers k [kg*256,+256) x cols [ch*64,+64) ----
    f32x4 acc0 = {0.f, 0.f, 0.f, 0.f}, acc1 = {0.f, 0.f, 0.f, 0.f};
    f32x4 acc2 = {0.f, 0.f, 0.f, 0.f}, acc3 = {0.f, 0.f, 0.f, 0.f};
#pragma unroll
    for (int kc = 0; kc < 8; ++kc) {
      const int f = (kg * 8 + kc) * 4 + lq;
      bf16x8 a = *(const bf16x8*)(AshB + f * 256 + ((l15 ^ (f & 15)) << 4));
      acc0 = __builtin_amdgcn_mfma_f32_16x16x32_bf16(a, __builtin_bit_cast(bf16x8, breg[kc * 4 + 0]), acc0, 0, 0, 0);
      acc1 = __builtin_amdgcn_mfma_f32_16x16x32_bf16(a, __builtin_bit_cast(bf16x8, breg[kc * 4 + 1]), acc1, 0, 0, 0);
      acc2 = __builtin_amdgcn_mfma_f32_16x16x32_bf16(a, __builtin_bit_cast(bf16x8, breg[kc * 4 + 2]), acc2, 0, 0, 0);
      acc3 = __builtin_amdgcn_mfma_f32_16x16x32_bf16(a, __builtin_bit_cast(bf16x8, breg[kc * 4 + 3]), acc3, 0, 0, 0);
    }
#pragma unroll
    for (int r_ = 0; r_ < 4; ++r_) {
      float* zr = Zsh + (kg * 16 + lq * 4 + r_) * 132 + ch * 64 + l15;
      zr[0] = acc0[r_]; zr[16] = acc1[r_]; zr[32] = acc2[r_]; zr[48] = acc3[r_];
    }
    __syncthreads();   // F

    // ---- gate pass: thread owns (row_own, hu) ----
    {
      const int xb = xsh[row_own];
      const float* tp = tsh + xb * 132;
      float z[4];
#pragma unroll
      for (int gate = 0; gate < 4; ++gate) {
        float zz = tp[gate * 32 + hu];
#pragma unroll
        for (int kgg = 0; kgg < 4; ++kgg)
          zz += Zsh[(kgg * 16 + row_own) * 132 + gate * 32 + hu];
        z[gate] = zz;
      }
      const float gv = tanhfast(z[0]);
      const float iv = sigf(z[1]);
      const float fv = sigf(z[2]);
      const float ov = sigf(z[3]);
      creg = gv * iv + creg * fv;
      const float hv = tanhfast(creg) * ov;
      hsh[row_own * 32 + hu] = f2bf(hv);
      if (s == S_ - 1) hfin[brow * H_ + colg] = hv;
    }
    __syncthreads();   // H

    // ---- packed publish: wave 0 stores the 1 KB slice + drains + flags ----
    // (vmcnt is wave-level, so wave 0's drain covers all its lanes' stores)
    if (tid < 64) {
      const unsigned long long* hp = (const unsigned long long*)hsh;
      unsigned short* dst = hX + ((s + 1) & 1) * HXBUF + bid * 512 + tid * 8;
      cstore8(dst, hp[tid * 2]);
      cstore8(dst + 4, hp[tid * 2 + 1]);
      asm volatile("s_waitcnt vmcnt(0)" ::: "memory");
      if (tid == 0)
        __hip_atomic_store(pub + bid * 32, (unsigned)(s + 2),
                           __ATOMIC_RELAXED, __HIP_MEMORY_SCOPE_AGENT);
    }
    // no barrier here: next-step polls/loads proceed; barrier B protects LDS
  }
}

// ---- p = hfin @ W_ph + b_p ; out = log_softmax(p) ----
__global__ void __launch_bounds__(256)
classify_kernel(const float* __restrict__ hfin, const float* __restrict__ Wph,
                const float* __restrict__ bp, float* __restrict__ out) {
  __shared__ float red[256 * 10];
  const int b = blockIdx.x, tid = threadIdx.x;
  float acc[10];
#pragma unroll
  for (int c = 0; c < 10; ++c) acc[c] = 0.f;
  for (int k = tid; k < H_; k += 256) {
    const float hv = hfin[b * H_ + k];
    const float* w = Wph + k * 10;
#pragma unroll
    for (int c = 0; c < 10; ++c) acc[c] += hv * w[c];
  }
#pragma unroll
  for (int c = 0; c < 10; ++c) red[tid * 10 + c] = acc[c];
  __syncthreads();
  for (int off = 128; off >= 1; off >>= 1) {
    if (tid < off) {
#pragma unroll
      for (int c = 0; c < 10; ++c) red[tid * 10 + c] += red[(tid + off) * 10 + c];
    }
    __syncthreads();
  }
  if (tid == 0) {
    float p[10];
    float m = -1e30f;
#pragma unroll
    for (int c = 0; c < 10; ++c) { p[c] = red[c] + bp[c]; m = fmaxf(m, p[c]); }
    float ssum = 0.f;
#pragma unroll
    for (int c = 0; c < 10; ++c) ssum += __expf(p[c] - m);
    const float lse = m + __logf(ssum);
#pragma unroll
    for (int c = 0; c < 10; ++c) out[b * 10 + c] = p[c] - lse;
  }
}

extern "C" void kernel_launch(void* const* d_in, const int* in_sizes, int n_in,
                              void* d_out, int out_size, void* d_ws, size_t ws_size,
                              hipStream_t stream) {
  (void)in_sizes; (void)n_in; (void)out_size; (void)ws_size;
  const int* x = (const int*)d_in[0];
  const float* emb = (const float*)d_in[1];
  const float* Wgx = (const float*)d_in[2];
  const float* Wgh = (const float*)d_in[3];
  const float* bg = (const float*)d_in[4];
  const float* Wix = (const float*)d_in[5];
  const float* Wih = (const float*)d_in[6];
  const float* bi = (const float*)d_in[7];
  const float* Wfx = (const float*)d_in[8];
  const float* Wfh = (const float*)d_in[9];
  const float* bf_ = (const float*)d_in[10];
  const float* Wox = (const float*)d_in[11];
  const float* Woh = (const float*)d_in[12];
  const float* bo = (const float*)d_in[13];
  const float* Wph = (const float*)d_in[14];
  const float* bp = (const float*)d_in[15];
  float* out = (float*)d_out;

  char* ws = (char*)d_ws;
  float* tokproj = (float*)ws;                                  // 2 MB
  unsigned short* WhT = (unsigned short*)(ws + 2097152);        // 8 MB
  unsigned short* hX = (unsigned short*)(ws + 10485760);        // 512 KB (2 bufs)
  float* hfin = (float*)(ws + 11010048);                        // 512 KB
  int* xT = (int*)(ws + 11538432);                              // 256 KB
  unsigned* pub = (unsigned*)(ws + 11800576);                   // 32 KB flags

  (void)hipMemsetAsync(pub, 0, 32768, stream);
  (void)hipFuncSetAttribute(reinterpret_cast<const void*>(lstm_scan),
                            hipFuncAttributeMaxDynamicSharedMemorySize, SMEM_TOTAL);

  tokproj_kernel<<<dim3(V_, 16), dim3(256), 0, stream>>>(
      emb, Wgx, Wix, Wfx, Wox, bg, bi, bf_, bo, tokproj);
  wht_kernel<<<dim3(4096), dim3(256), 0, stream>>>(Wgh, Wih, Wfh, Woh, WhT);
  xpose_kernel<<<dim3(256), dim3(256), 0, stream>>>(x, xT);
  lstm_scan<<<dim3(256), dim3(512), SMEM_TOTAL, stream>>>(
      xT, tokproj, WhT, hX, hfin, pub);
  classify_kernel<<<dim3(128), dim3(256), 0, stream>>>(hfin, Wph, bp, out);
}